// Round 7
// baseline (55.882 us; speedup 1.0000x reference)
//
#include <hip/hip_runtime.h>
#include <math.h>

#define NODES   100000
#define DIM     128
#define NEDGES  1600000          // 4 * 400000
#define NQUADS  (NEDGES / 4)     // 400000

#define LOG2E 1.44269504088896340736f

// clang-native vector types (accepted by __builtin_nontemporal_*)
typedef int   v4i __attribute__((ext_vector_type(4)));
typedef float v4f __attribute__((ext_vector_type(4)));

__device__ __forceinline__ float fast_sigmoid(float x) {
    return __builtin_amdgcn_rcpf(1.0f + __builtin_amdgcn_exp2f(-x * LOG2E));
}

__device__ __forceinline__ float dot4(v4f a, v4f b) {
    return a.x * b.x + a.y * b.y + a.z * b.z + a.w * b.w;
}

// Phase 1 (INSTRUMENTED: body repeated `reps` times; `zero`==0 at runtime but
// opaque to the compiler, so loads/stores cannot be hoisted/sunk and each rep
// re-executes the full memory traffic). Output identical to running once.
// 8 lanes/node, each lane owns 16 columns = 4 independent float4 loads (64B line).
__global__ __launch_bounds__(256) void node_proj_kernel(
    const float* __restrict__ h,
    const float* __restrict__ W,      // 256 floats: Wu | Wv
    const float* __restrict__ bias_ptr,
    float* __restrict__ pu,
    float* __restrict__ pv,
    int reps, int zero)
{
    const int tid   = blockIdx.x * 256 + threadIdx.x;
    const int lane8 = tid & 7;
    const int node  = tid >> 3;
    if (node >= NODES) return;

    const int c0 = lane8 * 16;
    const v4f u0 = reinterpret_cast<const v4f*>(W + c0)[0];
    const v4f u1 = reinterpret_cast<const v4f*>(W + c0)[1];
    const v4f u2 = reinterpret_cast<const v4f*>(W + c0)[2];
    const v4f u3 = reinterpret_cast<const v4f*>(W + c0)[3];
    const v4f w0 = reinterpret_cast<const v4f*>(W + DIM + c0)[0];
    const v4f w1 = reinterpret_cast<const v4f*>(W + DIM + c0)[1];
    const v4f w2 = reinterpret_cast<const v4f*>(W + DIM + c0)[2];
    const v4f w3 = reinterpret_cast<const v4f*>(W + DIM + c0)[3];
    const float b = bias_ptr[0];

    for (int rep = 0; rep < reps; ++rep) {
        const int n2 = node + rep * zero;   // == node at runtime; opaque to LLVM
        const v4f* hp = reinterpret_cast<const v4f*>(h + (size_t)n2 * DIM + c0);
        v4f h0 = hp[0], h1 = hp[1], h2 = hp[2], h3 = hp[3];

        float su = dot4(h0, u0) + dot4(h1, u1) + dot4(h2, u2) + dot4(h3, u3);
        float sv = dot4(h0, w0) + dot4(h1, w1) + dot4(h2, w2) + dot4(h3, w3);

        #pragma unroll
        for (int off = 4; off >= 1; off >>= 1) {
            su += __shfl_xor(su, off);
            sv += __shfl_xor(sv, off);
        }

        if (lane8 == 0) {
            pu[n2] = su;
            pv[n2] = sv + b;
        }
    }
}

// Phase 2: byte-identical to R6 (4 edges/thread, 8 gathers up front).
__global__ __launch_bounds__(256) void edge_score_kernel(
    const int*   __restrict__ src,
    const int*   __restrict__ dst,
    const float* __restrict__ pu,
    const float* __restrict__ pv,
    float* __restrict__ out)
{
    int i = blockIdx.x * 256 + threadIdx.x;
    if (i >= NQUADS) return;

    v4i s4 = reinterpret_cast<const v4i*>(src)[i];
    v4i d4 = reinterpret_cast<const v4i*>(dst)[i];

    float a0 = pu[s4.x], b0 = pv[d4.x];
    float a1 = pu[s4.y], b1 = pv[d4.y];
    float a2 = pu[s4.z], b2 = pv[d4.z];
    float a3 = pu[s4.w], b3 = pv[d4.w];

    v4f r;
    r.x = fast_sigmoid(a0 + b0);
    r.y = fast_sigmoid(a1 + b1);
    r.z = fast_sigmoid(a2 + b2);
    r.w = fast_sigmoid(a3 + b3);

    __builtin_nontemporal_store(r, reinterpret_cast<v4f*>(out) + i);
}

extern "C" void kernel_launch(void* const* d_in, const int* in_sizes, int n_in,
                              void* d_out, int out_size, void* d_ws, size_t ws_size,
                              hipStream_t stream) {
    const float* h    = (const float*)d_in[0];
    const int*   src  = (const int*)d_in[1];
    const int*   dst  = (const int*)d_in[2];
    const float* W    = (const float*)d_in[3];   // (1, 256)
    const float* bias = (const float*)d_in[4];   // (1,)
    float* out = (float*)d_out;

    float* pu = (float*)d_ws;                    // NODES floats
    float* pv = pu + NODES;                      // NODES floats

    const int reps = 9;                          // instrumentation: 1 real + 8 extra
    const int zero = in_sizes[4] - 1;            // bias has 1 element -> 0, opaque

    node_proj_kernel<<<(NODES * 8) / 256, 256, 0, stream>>>(h, W, bias, pu, pv, reps, zero);
    edge_score_kernel<<<(NQUADS + 255) / 256, 256, 0, stream>>>(src, dst, pu, pv, out);
}

// Round 8
// 31.688 us; speedup vs baseline: 1.7635x; 1.7635x over previous
//
#include <hip/hip_runtime.h>
#include <math.h>

#define NODES   100000
#define DIM     128
#define NEDGES  1600000          // 4 * 400000
#define NQUADS  (NEDGES / 4)     // 400000
#define NGROUPS (NODES / 8)      // 12500 32-lane groups, 8 nodes each

#define LOG2E 1.44269504088896340736f

// clang-native vector types (accepted by __builtin_nontemporal_*)
typedef int   v4i __attribute__((ext_vector_type(4)));
typedef float v4f __attribute__((ext_vector_type(4)));

__device__ __forceinline__ float fast_sigmoid(float x) {
    return __builtin_amdgcn_rcpf(1.0f + __builtin_amdgcn_exp2f(-x * LOG2E));
}

__device__ __forceinline__ float dot4(v4f a, v4f b) {
    return a.x * b.x + a.y * b.y + a.z * b.z + a.w * b.w;
}

// Phase 1: pu[n] = h[n].Wu, pv[n] = h[n].Wv + bias.
// 32 lanes cooperate per node (lane*16B -> each load instruction reads
// 512B contiguous per half-wave: 8 full lines, 4 lanes/line = minimal TA
// touches). Each thread processes 8 nodes -> 8 independent loads in flight
// before the first waitcnt (latency hiding), W slice reused from registers.
__global__ __launch_bounds__(256) void node_proj_kernel(
    const float* __restrict__ h,
    const float* __restrict__ W,      // 256 floats: Wu = W[0:128], Wv = W[128:256]
    const float* __restrict__ bias_ptr,
    float* __restrict__ pu,
    float* __restrict__ pv)
{
    const int tid  = blockIdx.x * 256 + threadIdx.x;
    const int lane = tid & 31;
    const int grp  = tid >> 5;
    if (grp >= NGROUPS) return;
    const int n0 = grp * 8;           // this group's 8 consecutive nodes

    const v4f wu = *reinterpret_cast<const v4f*>(W + lane * 4);
    const v4f wv = *reinterpret_cast<const v4f*>(W + DIM + lane * 4);
    const float b = bias_ptr[0];

    // 8 independent, per-instruction-coalesced row loads.
    const float* hb = h + (size_t)n0 * DIM + lane * 4;
    v4f hr[8];
    #pragma unroll
    for (int j = 0; j < 8; ++j)
        hr[j] = *reinterpret_cast<const v4f*>(hb + j * DIM);

    float su[8], sv[8];
    #pragma unroll
    for (int j = 0; j < 8; ++j) {
        su[j] = dot4(hr[j], wu);
        sv[j] = dot4(hr[j], wv);
    }

    // 16 interleaved 32-lane butterfly reductions.
    #pragma unroll
    for (int off = 16; off >= 1; off >>= 1) {
        #pragma unroll
        for (int j = 0; j < 8; ++j) {
            su[j] += __shfl_xor(su[j], off);
            sv[j] += __shfl_xor(sv[j], off);
        }
    }

    if (lane == 0) {
        v4f a0 = { su[0], su[1], su[2], su[3] };
        v4f a1 = { su[4], su[5], su[6], su[7] };
        v4f b0 = { sv[0] + b, sv[1] + b, sv[2] + b, sv[3] + b };
        v4f b1 = { sv[4] + b, sv[5] + b, sv[6] + b, sv[7] + b };
        *reinterpret_cast<v4f*>(pu + n0)     = a0;
        *reinterpret_cast<v4f*>(pu + n0 + 4) = a1;
        *reinterpret_cast<v4f*>(pv + n0)     = b0;
        *reinterpret_cast<v4f*>(pv + n0 + 4) = b1;
    }
}

// Phase 2: out[e] = sigmoid(pu[src[e]] + pv[dst[e]]).
// 4 edges/thread, 8 gathers issued up front. pu/pv (800 KB) are L2/L3-resident.
// TA line-lookup throughput (~3.2M gathers) is the floor here; ILP beyond this
// was shown null (R5). Only the out store is nontemporal.
__global__ __launch_bounds__(256) void edge_score_kernel(
    const int*   __restrict__ src,
    const int*   __restrict__ dst,
    const float* __restrict__ pu,
    const float* __restrict__ pv,
    float* __restrict__ out)
{
    int i = blockIdx.x * 256 + threadIdx.x;
    if (i >= NQUADS) return;

    v4i s4 = reinterpret_cast<const v4i*>(src)[i];
    v4i d4 = reinterpret_cast<const v4i*>(dst)[i];

    float a0 = pu[s4.x], b0 = pv[d4.x];
    float a1 = pu[s4.y], b1 = pv[d4.y];
    float a2 = pu[s4.z], b2 = pv[d4.z];
    float a3 = pu[s4.w], b3 = pv[d4.w];

    v4f r;
    r.x = fast_sigmoid(a0 + b0);
    r.y = fast_sigmoid(a1 + b1);
    r.z = fast_sigmoid(a2 + b2);
    r.w = fast_sigmoid(a3 + b3);

    __builtin_nontemporal_store(r, reinterpret_cast<v4f*>(out) + i);
}

extern "C" void kernel_launch(void* const* d_in, const int* in_sizes, int n_in,
                              void* d_out, int out_size, void* d_ws, size_t ws_size,
                              hipStream_t stream) {
    const float* h    = (const float*)d_in[0];
    const int*   src  = (const int*)d_in[1];
    const int*   dst  = (const int*)d_in[2];
    const float* W    = (const float*)d_in[3];   // (1, 256)
    const float* bias = (const float*)d_in[4];   // (1,)
    float* out = (float*)d_out;

    float* pu = (float*)d_ws;                    // NODES floats
    float* pv = pu + NODES;                      // NODES floats

    // Phase 1: 32 lanes/node, 8 nodes/thread -> 400k threads -> 1563 blocks.
    node_proj_kernel<<<(NGROUPS * 32 + 255) / 256, 256, 0, stream>>>(h, W, bias, pu, pv);

    // Phase 2: 4 edges/thread -> 400k threads.
    edge_score_kernel<<<(NQUADS + 255) / 256, 256, 0, stream>>>(src, dst, pu, pv, out);
}